// Round 8
// baseline (75454.572 us; speedup 1.0000x reference)
//
#include <hip/hip_runtime.h>
#include <math.h>

#define TT 8192
#define DD 1024
#define NWG 128   // 4 roles x 32 WGs
#define TPB 512   // 8 waves
#define MS ((size_t)DD * DD)
#define GCAP (1 << 14)

typedef __attribute__((ext_vector_type(4))) float f32x4;

// ---- LLC-coherent (cross-XCD) accesses: sc0 sc1, proven rounds 2-5 ----
__device__ __forceinline__ void vdrain() { asm volatile("s_waitcnt vmcnt(0)" ::: "memory"); }
__device__ __forceinline__ void st4_x(float* p, f32x4 v) {
  asm volatile("global_store_dwordx4 %0, %1, off sc0 sc1" :: "v"(p), "v"(v) : "memory");
}
__device__ __forceinline__ void stu_x(unsigned* p, unsigned v) {
  asm volatile("global_store_dword %0, %1, off sc0 sc1" :: "v"(p), "v"(v) : "memory");
}
__device__ __forceinline__ f32x4 ld4_x(const float* p) {
  f32x4 r;
  asm volatile("global_load_dwordx4 %0, %1, off sc0 sc1\n\ts_waitcnt vmcnt(0)"
               : "=&v"(r) : "v"(p) : "memory");
  return r;
}
__device__ __forceinline__ void ld4_x2(const float* p0, const float* p1, f32x4& a, f32x4& b) {
  asm volatile("global_load_dwordx4 %0, %2, off sc0 sc1\n\t"
               "global_load_dwordx4 %1, %3, off sc0 sc1\n\t"
               "s_waitcnt vmcnt(0)"
               : "=&v"(a), "=&v"(b) : "v"(p0), "v"(p1) : "memory");
}
__device__ __forceinline__ unsigned ldu_x(const unsigned* p) {
  unsigned r;
  asm volatile("global_load_dword %0, %1, off sc0 sc1\n\ts_waitcnt vmcnt(0)"
               : "=&v"(r) : "v"(p) : "memory");
  return r;
}

// Tag words padded to one 64B line each: [arr(4)][slot(8)][wg(32)] * 16 u32.
// arr: 0=Hx1(A done), 1=Hx2(C done), 2=G1(B done), 3=D2(D done).
__device__ __forceinline__ unsigned* tw(unsigned* tags, int arr, int slot, int idx) {
  return tags + (((arr * 8 + slot) * 32 + idx) << 4);
}

// Wave-parallel gate: lanes 0..31 poll 32 producer tag lines (32 LLC slices).
// On overrun: set global abort; every poll checks abort -> fast failure, no hang.
__device__ __forceinline__ void pollgate(const unsigned* base, unsigned* abortf,
                                         int ln, unsigned tgt) {
  const unsigned* p = base + ((ln & 31) << 4);
  int g = 0;
  for (;;) {
    unsigned v = tgt;
    if (ln < 32) v = ldu_x(p);
    if (__all((int)(v >= tgt))) return;
    if ((++g & 1023) == 0) {
      if (ldu_x(abortf)) return;
      if (g > GCAP) { stu_x(abortf, 1u); vdrain(); return; }
    }
  }
}

#define DOTROW(acc, ri)                                                              \
  acc += w[ri][0][4*c+0]*hv.x + w[ri][0][4*c+1]*hv.y + w[ri][0][4*c+2]*hv.z +        \
         w[ri][0][4*c+3]*hv.w + w[ri][1][4*c+0]*r0.x + w[ri][1][4*c+1]*r0.y +        \
         w[ri][1][4*c+2]*r0.z + w[ri][1][4*c+3]*r0.w + w[ri][2][4*c+0]*r1.x +        \
         w[ri][2][4*c+1]*r1.y + w[ri][2][4*c+2]*r1.z + w[ri][2][4*c+3]*r1.w;

__global__ void init_tags(unsigned* __restrict__ tags) {
  const int i = blockIdx.x * 256 + threadIdx.x;
  if (i < 4 * 8 * 32 * 16 + 16) tags[i] = 0u;
}

// Persistent 4-role CRSD (roles by blockIdx, all traffic LLC):
// role 0 = A: L1 pre-engine (Wh1,Wr1; r1 in LDS)  role 2 = B: L1 U-engine (U1)
// role 1 = C: L2 pre-engine (Wh2,Wr2; r2 in LDS)  role 3 = D: L2 U-engine (U2 + Wx2->p2)
__global__ __launch_bounds__(TPB, 1)
void crsd_seq(const float* __restrict__ pwx, const float* __restrict__ Wx,
              const float* __restrict__ Wh, const float* __restrict__ Wr,
              const float* __restrict__ Uw, const float* __restrict__ bias,
              float* __restrict__ out, float* __restrict__ arena,
              unsigned* __restrict__ tags) {
  __shared__ __align__(16) float sh_h[DD];
  __shared__ __align__(16) float sh_r[2 * DD];
  __shared__ __align__(16) float sh_x[DD];

  const int tid = threadIdx.x;
  const int wv = tid >> 6, ln = tid & 63;
  const int role = blockIdx.x >> 5, slot = blockIdx.x & 31;

  float* hx1 = arena;              // [8][DD]   A -> B,D (+A self)
  float* hx2 = arena + 8 * DD;     // [8][DD]   C -> D (+C self)
  float* g1b = arena + 16 * DD;    // [8][2DD]  B -> A
  float* g2b = arena + 32 * DD;    // [8][2DD]  D -> C
  float* p2b = arena + 48 * DD;    // [8][DD]   D -> C
  unsigned* abortf = tags + 4 * 8 * 32 * 16;

  if (role == 0 || role == 1) {
    // ================= pre-engine (A: L=0, C: L=1) =================
    const int L = role;
    float* hxL = L ? hx2 : hx1;
    float* gbL = L ? g2b : g1b;
    const int tagHxL = L ? 1 : 0;
    const int rb = 32 * slot + 4 * wv;
    const float* WhL = Wh + (size_t)L * MS;
    const float* WrL = Wr + (size_t)L * 2 * MS;
    float w[4][3][16];
#pragma unroll
    for (int ri = 0; ri < 4; ++ri) {
      const size_t ro = (size_t)(rb + ri) * DD + 16 * ln;
#pragma unroll
      for (int c = 0; c < 4; ++c) {
        f32x4 a = *(const f32x4*)&WhL[ro + 4 * c];
        w[ri][0][4*c+0]=a.x; w[ri][0][4*c+1]=a.y; w[ri][0][4*c+2]=a.z; w[ri][0][4*c+3]=a.w;
        f32x4 b0 = *(const f32x4*)&WrL[ro + 4 * c];
        w[ri][1][4*c+0]=b0.x; w[ri][1][4*c+1]=b0.y; w[ri][1][4*c+2]=b0.z; w[ri][1][4*c+3]=b0.w;
        f32x4 b1 = *(const f32x4*)&WrL[MS + ro + 4 * c];
        w[ri][2][4*c+0]=b1.x; w[ri][2][4*c+1]=b1.y; w[ri][2][4*c+2]=b1.z; w[ri][2][4*c+3]=b1.w;
      }
    }
    // h(-1)=0 in sh_h; r(-1)=0 in sh_r (integrated in LDS each tick from g)
    sh_h[tid] = 0.f; sh_h[tid + 512] = 0.f;
    sh_r[tid] = 0.f; sh_r[tid + 512] = 0.f; sh_r[tid + 1024] = 0.f; sh_r[tid + 1536] = 0.f;

    for (int t = 0; t < TT; ++t) {
      const int cu = t & 7, pg = (t - 1) & 7;
      // gates (waves poll concurrently)
      if (wv == 0) {
        if (L == 0) { if (t > 0) pollgate(tw(tags, 2, pg, 0), abortf, ln, (unsigned)t); }
        else pollgate(tw(tags, 3, cu, 0), abortf, ln, (unsigned)(t + 1));  // D done t: p2(t)+g2(t-1)
      } else if (wv == 1) {
        if (t > 0) pollgate(tw(tags, tagHxL, pg, 0), abortf, ln, (unsigned)t);  // peers done t-1
      } else if (wv == 2) {
        if (L == 0 && t >= 8) pollgate(tw(tags, 3, cu, 0), abortf, ln, (unsigned)(t - 7));  // bp
      }
      __syncthreads();
      // stage g(t-1) [2DD] + own-layer h(t-1) [DD]; integrate r in LDS
      if (t > 0) {
        f32x4 g4, h4;
        if (tid < 256) {
          ld4_x2(gbL + pg * 2 * DD + 4 * tid, hxL + pg * DD + 4 * tid, g4, h4);
          *(f32x4*)&sh_h[4 * tid] = h4;
        } else {
          g4 = ld4_x(gbL + pg * 2 * DD + 4 * tid);
        }
        f32x4 r4 = *(f32x4*)&sh_r[4 * tid];
        r4.x = 0.9f * r4.x + 0.1f * g4.x;
        r4.y = 0.9f * r4.y + 0.1f * g4.y;
        r4.z = 0.9f * r4.z + 0.1f * g4.z;
        r4.w = 0.9f * r4.w + 0.1f * g4.w;
        *(f32x4*)&sh_r[4 * tid] = r4;
      }
      f32x4 ex = {0.f, 0.f, 0.f, 0.f};
      if (ln == 0) {
        if (L == 0) ex = *(const f32x4*)&pwx[(size_t)t * DD + rb];
        else ex = ld4_x(p2b + cu * DD + rb);
      }
      __syncthreads();
      // 4 pre rows
      float a0 = 0.f, a1 = 0.f, a2 = 0.f, a3 = 0.f;
#pragma unroll
      for (int c = 0; c < 4; ++c) {
        const int j = 16 * ln + 4 * c;
        const f32x4 hv = *(const f32x4*)&sh_h[j];
        const f32x4 r0 = *(const f32x4*)&sh_r[j];
        const f32x4 r1 = *(const f32x4*)&sh_r[DD + j];
        DOTROW(a0, 0) DOTROW(a1, 1) DOTROW(a2, 2) DOTROW(a3, 3)
      }
#pragma unroll
      for (int off = 32; off; off >>= 1) {
        a0 += __shfl_xor(a0, off, 64); a1 += __shfl_xor(a1, off, 64);
        a2 += __shfl_xor(a2, off, 64); a3 += __shfl_xor(a3, off, 64);
      }
      if (ln == 0) {
        f32x4 hv4;
        hv4.x = tanhf(a0 + ex.x); hv4.y = tanhf(a1 + ex.y);
        hv4.z = tanhf(a2 + ex.z); hv4.w = tanhf(a3 + ex.w);
        st4_x(hxL + cu * DD + rb, hv4);
        if (L == 1) *(f32x4*)&out[(size_t)t * DD + rb] = hv4;
      }
      vdrain();
      __syncthreads();
      if (tid == 0) stu_x(tw(tags, tagHxL, cu, slot), (unsigned)(t + 1));
    }
  } else if (role == 2) {
    // ================= B: g1(t) = tanh(U1 h1(t)) =================
    const int gi0 = 64 * slot + 8 * wv;  // flat g row (k*DD+row)
    float u[8][16];
#pragma unroll
    for (int gi = 0; gi < 8; ++gi) {
      const int fr = gi0 + gi;
      const size_t ro = (size_t)(fr >> 10) * MS + (size_t)(fr & 1023) * DD + 16 * ln;
#pragma unroll
      for (int c = 0; c < 4; ++c) {
        f32x4 a = *(const f32x4*)&Uw[ro + 4 * c];
        u[gi][4*c+0]=a.x; u[gi][4*c+1]=a.y; u[gi][4*c+2]=a.z; u[gi][4*c+3]=a.w;
      }
    }
    for (int t = 0; t < TT - 1; ++t) {
      const int cu = t & 7;
      if (wv == 0) pollgate(tw(tags, 0, cu, 0), abortf, ln, (unsigned)(t + 1));
      __syncthreads();
      if (tid < 256) *(f32x4*)&sh_h[4 * tid] = ld4_x(hx1 + cu * DD + 4 * tid);
      __syncthreads();
      float ga[8] = {0.f,0.f,0.f,0.f,0.f,0.f,0.f,0.f};
#pragma unroll
      for (int c = 0; c < 4; ++c) {
        const f32x4 hv = *(const f32x4*)&sh_h[16 * ln + 4 * c];
#pragma unroll
        for (int gi = 0; gi < 8; ++gi)
          ga[gi] += u[gi][4*c+0]*hv.x + u[gi][4*c+1]*hv.y
                  + u[gi][4*c+2]*hv.z + u[gi][4*c+3]*hv.w;
      }
#pragma unroll
      for (int off = 32; off; off >>= 1) {
#pragma unroll
        for (int gi = 0; gi < 8; ++gi) ga[gi] += __shfl_xor(ga[gi], off, 64);
      }
      if (ln == 0) {
        f32x4 q0, q1;
        q0.x = tanhf(ga[0]); q0.y = tanhf(ga[1]); q0.z = tanhf(ga[2]); q0.w = tanhf(ga[3]);
        q1.x = tanhf(ga[4]); q1.y = tanhf(ga[5]); q1.z = tanhf(ga[6]); q1.w = tanhf(ga[7]);
        st4_x(g1b + cu * 2 * DD + gi0, q0);
        st4_x(g1b + cu * 2 * DD + gi0 + 4, q1);
      }
      vdrain();
      __syncthreads();
      if (tid == 0) stu_x(tw(tags, 2, cu, slot), (unsigned)(t + 1));
    }
  } else {
    // ================= D: p2(t) = Wx2 h1(t)+b2 ; g2(t-1) = tanh(U2 h2(t-1)) =================
    const int gi0 = 64 * slot + 8 * wv;
    const float* UL = Uw + 2 * MS;
    float u[8][16];
#pragma unroll
    for (int gi = 0; gi < 8; ++gi) {
      const int fr = gi0 + gi;
      const size_t ro = (size_t)(fr >> 10) * MS + (size_t)(fr & 1023) * DD + 16 * ln;
#pragma unroll
      for (int c = 0; c < 4; ++c) {
        f32x4 a = *(const f32x4*)&UL[ro + 4 * c];
        u[gi][4*c+0]=a.x; u[gi][4*c+1]=a.y; u[gi][4*c+2]=a.z; u[gi][4*c+3]=a.w;
      }
    }
    const int rp = 32 * slot + 4 * wv;
    float w2[4][16], b2[4];
#pragma unroll
    for (int ri = 0; ri < 4; ++ri) {
      const size_t ro = MS + (size_t)(rp + ri) * DD + 16 * ln;
#pragma unroll
      for (int c = 0; c < 4; ++c) {
        f32x4 a = *(const f32x4*)&Wx[ro + 4 * c];
        w2[ri][4*c+0]=a.x; w2[ri][4*c+1]=a.y; w2[ri][4*c+2]=a.z; w2[ri][4*c+3]=a.w;
      }
      b2[ri] = bias[DD + rp + ri];
    }
    for (int t = 0; t < TT; ++t) {
      const int cu = t & 7, pg = (t - 1) & 7;
      if (wv == 0) pollgate(tw(tags, 0, cu, 0), abortf, ln, (unsigned)(t + 1));       // h1(t)
      else if (wv == 1) { if (t > 0) pollgate(tw(tags, 1, pg, 0), abortf, ln, (unsigned)t); } // h2(t-1)
      __syncthreads();
      if (tid < 256) *(f32x4*)&sh_x[4 * tid] = ld4_x(hx1 + cu * DD + 4 * tid);
      else if (t > 0) {
        const int q = tid - 256;
        *(f32x4*)&sh_h[4 * q] = ld4_x(hx2 + pg * DD + 4 * q);
      }
      __syncthreads();
      float pa[4] = {0.f,0.f,0.f,0.f};
      float ga[8] = {0.f,0.f,0.f,0.f,0.f,0.f,0.f,0.f};
#pragma unroll
      for (int c = 0; c < 4; ++c) {
        const int j = 16 * ln + 4 * c;
        const f32x4 xv = *(const f32x4*)&sh_x[j];
#pragma unroll
        for (int ri = 0; ri < 4; ++ri)
          pa[ri] += w2[ri][4*c+0]*xv.x + w2[ri][4*c+1]*xv.y
                  + w2[ri][4*c+2]*xv.z + w2[ri][4*c+3]*xv.w;
        if (t > 0) {
          const f32x4 hv = *(const f32x4*)&sh_h[j];
#pragma unroll
          for (int gi = 0; gi < 8; ++gi)
            ga[gi] += u[gi][4*c+0]*hv.x + u[gi][4*c+1]*hv.y
                    + u[gi][4*c+2]*hv.z + u[gi][4*c+3]*hv.w;
        }
      }
#pragma unroll
      for (int off = 32; off; off >>= 1) {
#pragma unroll
        for (int ri = 0; ri < 4; ++ri) pa[ri] += __shfl_xor(pa[ri], off, 64);
#pragma unroll
        for (int gi = 0; gi < 8; ++gi) ga[gi] += __shfl_xor(ga[gi], off, 64);
      }
      if (ln == 0) {
        f32x4 p4;
        p4.x = pa[0] + b2[0]; p4.y = pa[1] + b2[1];
        p4.z = pa[2] + b2[2]; p4.w = pa[3] + b2[3];
        st4_x(p2b + cu * DD + rp, p4);
        if (t > 0) {
          f32x4 q0, q1;
          q0.x = tanhf(ga[0]); q0.y = tanhf(ga[1]); q0.z = tanhf(ga[2]); q0.w = tanhf(ga[3]);
          q1.x = tanhf(ga[4]); q1.y = tanhf(ga[5]); q1.z = tanhf(ga[6]); q1.w = tanhf(ga[7]);
          st4_x(g2b + pg * 2 * DD + gi0, q0);
          st4_x(g2b + pg * 2 * DD + gi0 + 4, q1);
        }
      }
      vdrain();
      __syncthreads();
      if (tid == 0) stu_x(tw(tags, 3, cu, slot), (unsigned)(t + 1));
    }
  }
}

// C[M][1024] = A[M][1024] @ W^T + bias   (W row-major [1024][1024])
__global__ __launch_bounds__(256)
void gemm_bias(const float* __restrict__ A, const float* __restrict__ W,
               const float* __restrict__ bias, float* __restrict__ C) {
  __shared__ float As[32][65];
  __shared__ float Ws[32][65];
  const int tid = threadIdx.x;
  const int bm = blockIdx.x * 64;
  const int bn = blockIdx.y * 64;
  const int ty = tid >> 4, tx = tid & 15;
  float acc[4][4] = {};
  for (int k0 = 0; k0 < DD; k0 += 32) {
#pragma unroll
    for (int p = 0; p < 2; ++p) {
      const int idx = tid + p * 256;
      const int r = idx >> 3;
      const int cf = idx & 7;
      float4 av = *(const float4*)&A[(size_t)(bm + r) * DD + k0 + cf * 4];
      As[cf*4+0][r] = av.x; As[cf*4+1][r] = av.y; As[cf*4+2][r] = av.z; As[cf*4+3][r] = av.w;
      float4 wv = *(const float4*)&W[(size_t)(bn + r) * DD + k0 + cf * 4];
      Ws[cf*4+0][r] = wv.x; Ws[cf*4+1][r] = wv.y; Ws[cf*4+2][r] = wv.z; Ws[cf*4+3][r] = wv.w;
    }
    __syncthreads();
#pragma unroll
    for (int kk = 0; kk < 32; ++kk) {
      float a[4], w[4];
#pragma unroll
      for (int e = 0; e < 4; ++e) { a[e] = As[kk][ty * 4 + e]; w[e] = Ws[kk][tx * 4 + e]; }
#pragma unroll
      for (int i = 0; i < 4; ++i)
#pragma unroll
        for (int j = 0; j < 4; ++j) acc[i][j] += a[i] * w[j];
    }
    __syncthreads();
  }
#pragma unroll
  for (int i = 0; i < 4; ++i) {
    const int m = bm + ty * 4 + i;
#pragma unroll
    for (int j = 0; j < 4; ++j) {
      const int n = bn + tx * 4 + j;
      C[(size_t)m * DD + n] = acc[i][j] + bias[n];
    }
  }
}

extern "C" void kernel_launch(void* const* d_in, const int* in_sizes, int n_in,
                              void* d_out, int out_size, void* d_ws, size_t ws_size,
                              hipStream_t stream) {
  const float* x  = (const float*)d_in[0];
  const float* Wx = (const float*)d_in[1];
  const float* Wh = (const float*)d_in[2];
  const float* Wr = (const float*)d_in[3];
  const float* U  = (const float*)d_in[4];
  const float* b  = (const float*)d_in[5];
  float* out = (float*)d_out;

  float* pwx = (float*)d_ws;                        // [T][D] fp32 = 32 MB
  float* arena = pwx + (size_t)TT * DD;             // 56*DD floats
  unsigned* tags = (unsigned*)(arena + 56 * DD);    // 4*8*32*16 + 16 u32 (64KB)

  hipLaunchKernelGGL(init_tags, dim3(65), dim3(256), 0, stream, tags);
  hipLaunchKernelGGL(gemm_bias, dim3(TT / 64, DD / 64), dim3(256), 0, stream,
                     x, Wx, b, pwx);  // layer-1 pwx = x @ Wx1^T + b1

  const float* pwxc = pwx;
  float* arenap = arena;
  unsigned* tagsp = tags;
  void* args[] = { (void*)&pwxc, (void*)&Wx, (void*)&Wh, (void*)&Wr,
                   (void*)&U, (void*)&b, (void*)&out, (void*)&arenap, (void*)&tagsp };
  hipLaunchCooperativeKernel((const void*)crsd_seq, dim3(NWG), dim3(TPB),
                             args, 0, stream);
}

// Round 11
// 74299.097 us; speedup vs baseline: 1.0156x; 1.0156x over previous
//
#include <hip/hip_runtime.h>
#include <math.h>

#define TT 8192
#define DD 1024
#define NWG 128   // 4 roles x 32 WGs
#define TPB 512   // 8 waves
#define MS ((size_t)DD * DD)
#define SENT 2.0f
#define GCAP (1 << 15)

typedef __attribute__((ext_vector_type(4))) float f32x4;

// ---- LLC-coherent (cross-XCD) accesses: sc0 sc1 ----
__device__ __forceinline__ void vdrain() { asm volatile("s_waitcnt vmcnt(0)" ::: "memory"); }
__device__ __forceinline__ void st4_x(float* p, f32x4 v) {
  asm volatile("global_store_dwordx4 %0, %1, off sc0 sc1" :: "v"(p), "v"(v) : "memory");
}
__device__ __forceinline__ void stu_x(unsigned* p, unsigned v) {
  asm volatile("global_store_dword %0, %1, off sc0 sc1" :: "v"(p), "v"(v) : "memory");
}
__device__ __forceinline__ f32x4 ld4_x(const float* p) {
  f32x4 r;
  asm volatile("global_load_dwordx4 %0, %1, off sc0 sc1\n\ts_waitcnt vmcnt(0)"
               : "=&v"(r) : "v"(p) : "memory");
  return r;
}
__device__ __forceinline__ unsigned ldu_x(const unsigned* p) {
  unsigned r;
  asm volatile("global_load_dword %0, %1, off sc0 sc1\n\ts_waitcnt vmcnt(0)"
               : "=&v"(r) : "v"(p) : "memory");
  return r;
}

// Data-as-flag: poll own 16B chunk until no lane equals SENT. Capped + abort.
__device__ __forceinline__ f32x4 pollload(const float* p, unsigned* abortf) {
  f32x4 v = ld4_x(p);
  int g = 0;
  while (v.x == SENT || v.y == SENT || v.z == SENT || v.w == SENT) {
    ++g;
    if ((g & 255) == 16) {
      if (ldu_x(abortf) != 0u) break;
      if (g > GCAP) { stu_x(abortf, 1u); vdrain(); break; }
    }
    v = ld4_x(p);
  }
  return v;
}

// arena: hx1[8][DD] | hx2[8][DD] | g1b[8][2DD] | g2b[8][2DD] | p2b[8][DD] = 56*DD
__global__ void init_arena(float* __restrict__ arena, unsigned* __restrict__ tags) {
  const int idx = blockIdx.x * 256 + threadIdx.x;
  if (idx < 56 * DD) {
    float v = SENT;
    if (idx < 8 * DD) { if ((idx >> 10) == 7) v = 0.f; }                  // hx1 slot7 = h1(-1)=0
    else if (idx < 16 * DD) { if (((idx - 8 * DD) >> 10) == 7) v = 0.f; } // hx2 slot7 = h2(-1)=0
    else if (idx < 32 * DD) { if (((idx - 16 * DD) >> 11) == 7) v = 0.f; }// g1b slot7 = g1(-1)=0
    arena[idx] = v;
  }
  if (blockIdx.x == 0) {
#pragma unroll
    for (int q = 0; q < 4; ++q) tags[threadIdx.x + 256 * q] = 0u;  // stamps + abort
  }
}

// Persistent 4-role CRSD, data-as-flag exchange, z=Wr*r kept in registers.
// role 0 = A: L1 pre (Wh1,Wr1; z1 in regs)   role 2 = B: L1 U-engine (U1 -> g1)
// role 1 = C: L2 pre (Wh2,Wr2; z2 in regs)   role 3 = D: L2 U-engine (U2 -> g2; Wx2 -> p2)
// Poison schedule: slot (t-4)&7 at t>=4, PLUS early poison of slot 7 (init-zero
// state) at t==1 — round-9/10 bug: slot 7 was republished at tick 7 un-poisoned,
// so consumers could read the init zeros as valid tick-7 data.
__global__ __launch_bounds__(TPB, 1)
void crsd_seq(const float* __restrict__ pwx, const float* __restrict__ Wx,
              const float* __restrict__ Wh, const float* __restrict__ Wr,
              const float* __restrict__ Uw, const float* __restrict__ bias,
              float* __restrict__ out, float* __restrict__ arena,
              unsigned* __restrict__ tags) {
  __shared__ __align__(16) float sh_h[DD];
  __shared__ __align__(16) float sh_g[2 * DD];
  __shared__ __align__(16) float sh_x[DD];

  const int tid = threadIdx.x;
  const int wv = tid >> 6, ln = tid & 63;
  const int role = blockIdx.x >> 5, slot = blockIdx.x & 31;

  float* hx1 = arena;
  float* hx2 = arena + 8 * DD;
  float* g1b = arena + 16 * DD;
  float* g2b = arena + 32 * DD;
  float* p2b = arena + 48 * DD;
  unsigned* stamp32 = tags;        // 32 D-block stamps, 64B-padded (idx<<4)
  unsigned* abortf = tags + 512;

  const f32x4 sentv = {SENT, SENT, SENT, SENT};

  if (role <= 1) {
    // ================= pre-engine (A: L=0, C: L=1) =================
    const int L = role;
    float* hxL = L ? hx2 : hx1;
    float* gbL = L ? g2b : g1b;
    const int rb = 32 * slot + 4 * wv;   // 4 owned rows
    const float* WhL = Wh + (size_t)L * MS;
    const float* WrL = Wr + (size_t)L * 2 * MS;
    float w[4][3][16];
#pragma unroll
    for (int ri = 0; ri < 4; ++ri) {
#pragma unroll
      for (int c = 0; c < 4; ++c) {
        const size_t ro = (size_t)(rb + ri) * DD + 4 * ln + 256 * c;
        f32x4 a = *(const f32x4*)&WhL[ro];
        w[ri][0][4*c+0]=a.x; w[ri][0][4*c+1]=a.y; w[ri][0][4*c+2]=a.z; w[ri][0][4*c+3]=a.w;
        f32x4 b0 = *(const f32x4*)&WrL[ro];
        w[ri][1][4*c+0]=b0.x; w[ri][1][4*c+1]=b0.y; w[ri][1][4*c+2]=b0.z; w[ri][1][4*c+3]=b0.w;
        f32x4 b1 = *(const f32x4*)&WrL[MS + ro];
        w[ri][2][4*c+0]=b1.x; w[ri][2][4*c+1]=b1.y; w[ri][2][4*c+2]=b1.z; w[ri][2][4*c+3]=b1.w;
      }
    }
    float zr[4] = {0.f, 0.f, 0.f, 0.f};   // z = Wr*r rows (lane 0)

    for (int t = 0; t < TT; ++t) {
      const int cu = t & 7, pg = (t - 1) & 7;
      const int gs = L ? cu : pg;   // A consumes g1(t-1) [slot t-1]; C consumes D's tick-t publish

      // ---- stage h(t-1) ----
      if (tid < 256)
        *(f32x4*)&sh_h[4 * tid] = pollload(hxL + pg * DD + 4 * tid, abortf);
      __syncthreads();

      // ---- wave 0: gate (A, t>=4 only) + poison own-block rows ----
      // Regular: slot (t-4)&7 at t>=4.  Early: slot 7 (init zeros) at t==1 —
      // safe: h-poll above proved all own-role blocks finished tick t-1, which
      // (A) covers A's tick-0 slot-7 read, (C) implies all D finished tick-0
      // staging (their hx2 slot-7 read) via C's tick-0 g2-poll.
      if (wv == 0 && (t >= 4 || t == 1)) {
        if (t >= 4 && L == 0) {
          const unsigned tgt = (unsigned)(t - 3);   // all D consumed h1(t-4)
          const unsigned* sp = stamp32 + ((ln & 31) << 4);
          int g = 0;
          for (;;) {
            unsigned v = tgt;
            if (ln < 32) v = ldu_x(sp);
            if (__all((int)(v >= tgt))) break;
            if ((++g & 255) == 0) {
              if (ldu_x(abortf)) break;
              if (g > GCAP) { stu_x(abortf, 1u); vdrain(); break; }
            }
          }
        }
        const int ps = (t >= 4) ? ((t - 4) & 7) : 7;
        if (ln < 8)
          st4_x(hxL + ps * DD + 32 * slot + 4 * ln, sentv);
        vdrain();
      }

      // ---- Wh*h(t-1) partials (overlaps g-wait) ----
      float wp[4] = {0.f, 0.f, 0.f, 0.f};
#pragma unroll
      for (int c = 0; c < 4; ++c) {
        const int j = 4 * ln + 256 * c;
        const f32x4 hv = *(const f32x4*)&sh_h[j];
#pragma unroll
        for (int ri = 0; ri < 4; ++ri)
          wp[ri] += w[ri][0][4*c+0]*hv.x + w[ri][0][4*c+1]*hv.y
                  + w[ri][0][4*c+2]*hv.z + w[ri][0][4*c+3]*hv.w;
      }
      f32x4 ex = {0.f, 0.f, 0.f, 0.f};
      if (L == 0 && ln == 0) ex = *(const f32x4*)&pwx[(size_t)t * DD + rb];

      // ---- stage g (the critical leg) ----
      *(f32x4*)&sh_g[4 * tid] = pollload(gbL + gs * 2 * DD + 4 * tid, abortf);
      __syncthreads();   // also orders wave-0 poison before all publishes below
      if (L == 1 && ln == 0) ex = ld4_x(p2b + cu * DD + rb);  // ordered behind g2

      // ---- v = Wr*g partials; z update; publish h(t) ----
      float vp[4] = {0.f, 0.f, 0.f, 0.f};
#pragma unroll
      for (int c = 0; c < 4; ++c) {
        const int j = 4 * ln + 256 * c;
        const f32x4 g0 = *(const f32x4*)&sh_g[j];
        const f32x4 g1 = *(const f32x4*)&sh_g[DD + j];
#pragma unroll
        for (int ri = 0; ri < 4; ++ri)
          vp[ri] += w[ri][1][4*c+0]*g0.x + w[ri][1][4*c+1]*g0.y
                  + w[ri][1][4*c+2]*g0.z + w[ri][1][4*c+3]*g0.w
                  + w[ri][2][4*c+0]*g1.x + w[ri][2][4*c+1]*g1.y
                  + w[ri][2][4*c+2]*g1.z + w[ri][2][4*c+3]*g1.w;
      }
#pragma unroll
      for (int off = 32; off; off >>= 1) {
#pragma unroll
        for (int ri = 0; ri < 4; ++ri) {
          wp[ri] += __shfl_xor(wp[ri], off, 64);
          vp[ri] += __shfl_xor(vp[ri], off, 64);
        }
      }
      if (ln == 0) {
        f32x4 hv4;
        zr[0] = 0.9f * zr[0] + 0.1f * vp[0];
        zr[1] = 0.9f * zr[1] + 0.1f * vp[1];
        zr[2] = 0.9f * zr[2] + 0.1f * vp[2];
        zr[3] = 0.9f * zr[3] + 0.1f * vp[3];
        hv4.x = tanhf(wp[0] + zr[0] + ex.x);
        hv4.y = tanhf(wp[1] + zr[1] + ex.y);
        hv4.z = tanhf(wp[2] + zr[2] + ex.z);
        hv4.w = tanhf(wp[3] + zr[3] + ex.w);
        st4_x(hxL + cu * DD + rb, hv4);          // data IS the flag
        if (L == 1) *(f32x4*)&out[(size_t)t * DD + rb] = hv4;
      }
    }
  } else if (role == 2) {
    // ================= B: g1(t) = tanh(U1 h1(t)) =================
    const int gi0 = 64 * slot + 8 * wv;   // 8 owned flat g rows
    float u[8][16];
#pragma unroll
    for (int gi = 0; gi < 8; ++gi) {
      const int fr = gi0 + gi;
      const size_t ro = (size_t)(fr >> 10) * MS + (size_t)(fr & 1023) * DD;
#pragma unroll
      for (int c = 0; c < 4; ++c) {
        f32x4 a = *(const f32x4*)&Uw[ro + 4 * ln + 256 * c];
        u[gi][4*c+0]=a.x; u[gi][4*c+1]=a.y; u[gi][4*c+2]=a.z; u[gi][4*c+3]=a.w;
      }
    }
    for (int t = 0; t < TT - 1; ++t) {
      const int cu = t & 7;
      if (tid < 256)
        *(f32x4*)&sh_h[4 * tid] = pollload(hx1 + cu * DD + 4 * tid, abortf);
      __syncthreads();
      // poison own g chunks: regular slot (t-4)&7 at t>=4; early slot 7 at t==1
      // (h-poll saw h1(t) => all A past tick t>=1 => A's tick-0 slot-7 g-read done)
      if ((t >= 4 || t == 1) && ln == 0) {
        const int ps = (t >= 4) ? ((t - 4) & 7) : 7;
        st4_x(g1b + ps * 2 * DD + gi0, sentv);
        st4_x(g1b + ps * 2 * DD + gi0 + 4, sentv);
      }
      float ga[8] = {0.f,0.f,0.f,0.f,0.f,0.f,0.f,0.f};
#pragma unroll
      for (int c = 0; c < 4; ++c) {
        const f32x4 hv = *(const f32x4*)&sh_h[4 * ln + 256 * c];
#pragma unroll
        for (int gi = 0; gi < 8; ++gi)
          ga[gi] += u[gi][4*c+0]*hv.x + u[gi][4*c+1]*hv.y
                  + u[gi][4*c+2]*hv.z + u[gi][4*c+3]*hv.w;
      }
#pragma unroll
      for (int off = 32; off; off >>= 1) {
#pragma unroll
        for (int gi = 0; gi < 8; ++gi) ga[gi] += __shfl_xor(ga[gi], off, 64);
      }
      vdrain();   // poison drained before publish (same wave)
      if (ln == 0) {
        f32x4 q0, q1;
        q0.x = tanhf(ga[0]); q0.y = tanhf(ga[1]); q0.z = tanhf(ga[2]); q0.w = tanhf(ga[3]);
        q1.x = tanhf(ga[4]); q1.y = tanhf(ga[5]); q1.z = tanhf(ga[6]); q1.w = tanhf(ga[7]);
        st4_x(g1b + cu * 2 * DD + gi0, q0);
        st4_x(g1b + cu * 2 * DD + gi0 + 4, q1);
      }
      __syncthreads();   // protect sh_h before next staging
    }
  } else {
    // ===== D: p2(t) = Wx2 h1(t)+b2 ; g2(t-1) = tanh(U2 h2(t-1)); slot = publish tick =====
    const int gi0 = 64 * slot + 8 * wv;
    const int rp = 32 * slot + 4 * wv;
    const float* UL = Uw + 2 * MS;
    float u[8][16];
#pragma unroll
    for (int gi = 0; gi < 8; ++gi) {
      const int fr = gi0 + gi;
      const size_t ro = (size_t)(fr >> 10) * MS + (size_t)(fr & 1023) * DD;
#pragma unroll
      for (int c = 0; c < 4; ++c) {
        f32x4 a = *(const f32x4*)&UL[ro + 4 * ln + 256 * c];
        u[gi][4*c+0]=a.x; u[gi][4*c+1]=a.y; u[gi][4*c+2]=a.z; u[gi][4*c+3]=a.w;
      }
    }
    float w2[4][16], b2[4];
#pragma unroll
    for (int ri = 0; ri < 4; ++ri) {
      const size_t ro = MS + (size_t)(rp + ri) * DD;
#pragma unroll
      for (int c = 0; c < 4; ++c) {
        f32x4 a = *(const f32x4*)&Wx[ro + 4 * ln + 256 * c];
        w2[ri][4*c+0]=a.x; w2[ri][4*c+1]=a.y; w2[ri][4*c+2]=a.z; w2[ri][4*c+3]=a.w;
      }
      b2[ri] = bias[DD + rp + ri];
    }
    for (int t = 0; t < TT; ++t) {
      const int cu = t & 7, pg = (t - 1) & 7;
      if (tid < 256)
        *(f32x4*)&sh_x[4 * tid] = pollload(hx1 + cu * DD + 4 * tid, abortf);
      else {
        const int q = tid - 256;
        *(f32x4*)&sh_h[4 * q] = pollload(hx2 + pg * DD + 4 * q, abortf);
      }
      __syncthreads();
      if (tid == 0) stu_x(stamp32 + (slot << 4), (unsigned)(t + 1));  // consumed h1(t)
      // g2b starts all-SENT (no zero-init slot): regular poison only.
      if (t >= 4 && ln == 0) {
        const int ps = (t - 4) & 7;
        st4_x(g2b + ps * 2 * DD + gi0, sentv);
        st4_x(g2b + ps * 2 * DD + gi0 + 4, sentv);
      }
      float pa[4] = {0.f,0.f,0.f,0.f};
      float ga[8] = {0.f,0.f,0.f,0.f,0.f,0.f,0.f,0.f};
#pragma unroll
      for (int c = 0; c < 4; ++c) {
        const int j = 4 * ln + 256 * c;
        const f32x4 xv = *(const f32x4*)&sh_x[j];
        const f32x4 hv = *(const f32x4*)&sh_h[j];
#pragma unroll
        for (int ri = 0; ri < 4; ++ri)
          pa[ri] += w2[ri][4*c+0]*xv.x + w2[ri][4*c+1]*xv.y
                  + w2[ri][4*c+2]*xv.z + w2[ri][4*c+3]*xv.w;
#pragma unroll
        for (int gi = 0; gi < 8; ++gi)
          ga[gi] += u[gi][4*c+0]*hv.x + u[gi][4*c+1]*hv.y
                  + u[gi][4*c+2]*hv.z + u[gi][4*c+3]*hv.w;
      }
#pragma unroll
      for (int off = 32; off; off >>= 1) {
#pragma unroll
        for (int ri = 0; ri < 4; ++ri) pa[ri] += __shfl_xor(pa[ri], off, 64);
#pragma unroll
        for (int gi = 0; gi < 8; ++gi) ga[gi] += __shfl_xor(ga[gi], off, 64);
      }
      if (ln == 0) {
        f32x4 p4;
        p4.x = pa[0] + b2[0]; p4.y = pa[1] + b2[1];
        p4.z = pa[2] + b2[2]; p4.w = pa[3] + b2[3];
        st4_x(p2b + cu * DD + rp, p4);
      }
      vdrain();   // orders poison + p2 before the g2 flag-publish (same wave)
      if (ln == 0) {
        f32x4 q0, q1;
        q0.x = tanhf(ga[0]); q0.y = tanhf(ga[1]); q0.z = tanhf(ga[2]); q0.w = tanhf(ga[3]);
        q1.x = tanhf(ga[4]); q1.y = tanhf(ga[5]); q1.z = tanhf(ga[6]); q1.w = tanhf(ga[7]);
        st4_x(g2b + cu * 2 * DD + gi0, q0);
        st4_x(g2b + cu * 2 * DD + gi0 + 4, q1);
      }
      __syncthreads();
    }
  }
}

// C[M][1024] = A[M][1024] @ W^T + bias   (W row-major [1024][1024])
__global__ __launch_bounds__(256)
void gemm_bias(const float* __restrict__ A, const float* __restrict__ W,
               const float* __restrict__ bias, float* __restrict__ C) {
  __shared__ float As[32][65];
  __shared__ float Ws[32][65];
  const int tid = threadIdx.x;
  const int bm = blockIdx.x * 64;
  const int bn = blockIdx.y * 64;
  const int ty = tid >> 4, tx = tid & 15;
  float acc[4][4] = {};
  for (int k0 = 0; k0 < DD; k0 += 32) {
#pragma unroll
    for (int p = 0; p < 2; ++p) {
      const int idx = tid + p * 256;
      const int r = idx >> 3;
      const int cf = idx & 7;
      float4 av = *(const float4*)&A[(size_t)(bm + r) * DD + k0 + cf * 4];
      As[cf*4+0][r] = av.x; As[cf*4+1][r] = av.y; As[cf*4+2][r] = av.z; As[cf*4+3][r] = av.w;
      float4 wv = *(const float4*)&W[(size_t)(bn + r) * DD + k0 + cf * 4];
      Ws[cf*4+0][r] = wv.x; Ws[cf*4+1][r] = wv.y; Ws[cf*4+2][r] = wv.z; Ws[cf*4+3][r] = wv.w;
    }
    __syncthreads();
#pragma unroll
    for (int kk = 0; kk < 32; ++kk) {
      float a[4], w[4];
#pragma unroll
      for (int e = 0; e < 4; ++e) { a[e] = As[kk][ty * 4 + e]; w[e] = Ws[kk][tx * 4 + e]; }
#pragma unroll
      for (int i = 0; i < 4; ++i)
#pragma unroll
        for (int j = 0; j < 4; ++j) acc[i][j] += a[i] * w[j];
    }
    __syncthreads();
  }
#pragma unroll
  for (int i = 0; i < 4; ++i) {
    const int m = bm + ty * 4 + i;
#pragma unroll
    for (int j = 0; j < 4; ++j) {
      const int n = bn + tx * 4 + j;
      C[(size_t)m * DD + n] = acc[i][j] + bias[n];
    }
  }
}

extern "C" void kernel_launch(void* const* d_in, const int* in_sizes, int n_in,
                              void* d_out, int out_size, void* d_ws, size_t ws_size,
                              hipStream_t stream) {
  const float* x  = (const float*)d_in[0];
  const float* Wx = (const float*)d_in[1];
  const float* Wh = (const float*)d_in[2];
  const float* Wr = (const float*)d_in[3];
  const float* U  = (const float*)d_in[4];
  const float* b  = (const float*)d_in[5];
  float* out = (float*)d_out;

  float* pwx = (float*)d_ws;                     // [T][D] fp32 = 32 MB
  float* arena = pwx + (size_t)TT * DD;          // 56*DD floats
  unsigned* tags = (unsigned*)(arena + 56 * DD); // 1024 u32: stamps(32x16) + abort

  hipLaunchKernelGGL(init_arena, dim3(224), dim3(256), 0, stream, arena, tags);
  hipLaunchKernelGGL(gemm_bias, dim3(TT / 64, DD / 64), dim3(256), 0, stream,
                     x, Wx, b, pwx);  // layer-1 pwx = x @ Wx1^T + b1

  const float* pwxc = pwx;
  float* arenap = arena;
  unsigned* tagsp = tags;
  void* args[] = { (void*)&pwxc, (void*)&Wx, (void*)&Wh, (void*)&Wr,
                   (void*)&U, (void*)&b, (void*)&out, (void*)&arenap, (void*)&tagsp };
  hipLaunchCooperativeKernel((const void*)crsd_seq, dim3(NWG), dim3(TPB),
                             args, 0, stream);
}

// Round 12
// 45792.294 us; speedup vs baseline: 1.6478x; 1.6225x over previous
//
#include <hip/hip_runtime.h>
#include <math.h>

#define TT 8192
#define DD 1024
#define LWG 64    // WGs per layer
#define NWG 128   // total
#define TPB 512   // 8 waves; each wave owns 2 pre-rows + 4 U-rows
#define GCAP (1 << 14)

typedef __attribute__((ext_vector_type(2))) float f32x2;
typedef __attribute__((ext_vector_type(4))) float f32x4;

// ---- LLC-coherent (cross-XCD) accesses: sc0 sc1 ----
__device__ __forceinline__ void vdrain() { asm volatile("s_waitcnt vmcnt(0)" ::: "memory"); }
__device__ __forceinline__ void st2_x(float* p, f32x2 v) {
  asm volatile("global_store_dwordx2 %0, %1, off sc0 sc1" :: "v"(p), "v"(v) : "memory");
}
__device__ __forceinline__ void stu_x(unsigned* p, unsigned v) {
  asm volatile("global_store_dword %0, %1, off sc0 sc1" :: "v"(p), "v"(v) : "memory");
}
__device__ __forceinline__ f32x4 ld4_x(const float* p) {
  f32x4 r;
  asm volatile("global_load_dwordx4 %0, %1, off sc0 sc1\n\ts_waitcnt vmcnt(0)"
               : "=&v"(r) : "v"(p) : "memory");
  return r;
}
__device__ __forceinline__ void ld4_x2(const float* p0, const float* p1, f32x4& a, f32x4& b) {
  asm volatile("global_load_dwordx4 %0, %2, off sc0 sc1\n\t"
               "global_load_dwordx4 %1, %3, off sc0 sc1\n\t"
               "s_waitcnt vmcnt(0)"
               : "=&v"(a), "=&v"(b) : "v"(p0), "v"(p1) : "memory");
}
__device__ __forceinline__ unsigned ldu_x(const unsigned* p) {
  unsigned r;
  asm volatile("global_load_dword %0, %1, off sc0 sc1\n\ts_waitcnt vmcnt(0)"
               : "=&v"(r) : "v"(p) : "memory");
  return r;
}

// Tag words PADDED to one 64B line each: [kind(2)][layer(2)][slot(8)][LWG] x16 u32.
// kind 0 = h ready, kind 1 = r ready. Producer g stores (t>>3)+1 after data drains.
__device__ __forceinline__ unsigned* tagp(unsigned* tg, int kind, int layer,
                                          int slot, int idx) {
  return tg + (((((kind * 2 + layer) * 8 + slot) * LWG) + idx) << 4);
}

// All-64-lane poll of 64 padded tag lines (one producer per lane, 64 LLC lines).
// s_sleep backoff cuts fabric pressure; abort flag -> fast failure, no hang.
__device__ __forceinline__ void pollgate(const unsigned* base, unsigned* abortf,
                                         int ln, unsigned tgt) {
  const unsigned* p = base + (ln << 4);
  int g = 0;
  for (;;) {
    const unsigned v = ldu_x(p);
    if (__all((int)(v >= tgt))) return;
    if ((++g & 255) == 0) {
      if (ldu_x(abortf)) return;
      if (g > GCAP) { stu_x(abortf, 1u); vdrain(); return; }
    }
    __builtin_amdgcn_s_sleep(1);
  }
}

// arena: h1s[8*DD] | h2s[8*DD] | r1s[8*2DD] | r2s[8*2DD] = 48*DD floats (zeros ok)
__global__ void init_arena(float* __restrict__ arena, unsigned* __restrict__ tg) {
  const int idx = blockIdx.x * 256 + threadIdx.x;
  if (idx < 48 * DD) arena[idx] = 0.f;
  if (idx < 2 * 2 * 8 * LWG * 16 + 16) tg[idx] = 0u;
}

// Persistent dataflow 2-layer CRSD (round-5 structure, padded tags).
// WGs 0..63: layer 1; 64..127: layer 2 (consumes h1_t same tick, one tick behind).
// Wave wv of g owns pre-rows rb=g*16+2*wv, rb+1 and U-rows (k,rb),(k,rb+1).
__global__ __launch_bounds__(TPB, 1)
void crsd_seq(const float* __restrict__ pwx, const float* __restrict__ Wx,
              const float* __restrict__ Wh, const float* __restrict__ Wr,
              const float* __restrict__ Uw, const float* __restrict__ bias,
              float* __restrict__ out, float* __restrict__ arena,
              unsigned* __restrict__ tg) {
  const int wg = blockIdx.x, tid = threadIdx.x;
  const int wv = tid >> 6, ln = tid & 63;
  const int layer = wg >> 6, g = wg & 63;
  const int rb = g * 16 + 2 * wv;
  const size_t MS = (size_t)DD * DD;

  float* h1s = arena;
  float* h2s = arena + 8 * DD;
  float* r1s = arena + 16 * DD;
  float* r2s = arena + 32 * DD;
  float* hS = layer ? h2s : h1s;
  float* rS = layer ? r2s : r1s;
  unsigned* abortf = tg + 2 * 2 * 8 * LWG * 16;

  __shared__ __align__(16) float sh_x[DD];
  __shared__ __align__(16) float sh_h[DD];
  __shared__ __align__(16) float sh_r[2 * DD];

  const float* Whp = Wh + (size_t)layer * MS;
  const float* Wrp = Wr + (size_t)layer * 2 * MS;
  const float* Up  = Uw + (size_t)layer * 2 * MS;

  // ---- one-time weight load into registers (2 pre-rows + 4 U-rows per wave) ----
  float wh[2][16], wr[2][2][16], wx[2][16], uw[2][2][16];
#pragma unroll
  for (int ri = 0; ri < 2; ++ri) {
    const int row = rb + ri;
#pragma unroll
    for (int c = 0; c < 4; ++c) {
      const int j = 4 * ln + 256 * c;
      f32x4 a = *(const f32x4*)&Whp[(size_t)row * DD + j];
      wh[ri][4*c+0]=a.x; wh[ri][4*c+1]=a.y; wh[ri][4*c+2]=a.z; wh[ri][4*c+3]=a.w;
      f32x4 b0 = *(const f32x4*)&Wrp[(size_t)row * DD + j];
      wr[ri][0][4*c+0]=b0.x; wr[ri][0][4*c+1]=b0.y; wr[ri][0][4*c+2]=b0.z; wr[ri][0][4*c+3]=b0.w;
      f32x4 b1 = *(const f32x4*)&Wrp[MS + (size_t)row * DD + j];
      wr[ri][1][4*c+0]=b1.x; wr[ri][1][4*c+1]=b1.y; wr[ri][1][4*c+2]=b1.z; wr[ri][1][4*c+3]=b1.w;
      if (layer) {
        f32x4 xw = *(const f32x4*)&Wx[MS + (size_t)row * DD + j];
        wx[ri][4*c+0]=xw.x; wx[ri][4*c+1]=xw.y; wx[ri][4*c+2]=xw.z; wx[ri][4*c+3]=xw.w;
      } else {
        wx[ri][4*c+0]=0.f; wx[ri][4*c+1]=0.f; wx[ri][4*c+2]=0.f; wx[ri][4*c+3]=0.f;
      }
      f32x4 u0 = *(const f32x4*)&Up[(size_t)row * DD + j];
      uw[0][ri][4*c+0]=u0.x; uw[0][ri][4*c+1]=u0.y; uw[0][ri][4*c+2]=u0.z; uw[0][ri][4*c+3]=u0.w;
      f32x4 u1 = *(const f32x4*)&Up[MS + (size_t)row * DD + j];
      uw[1][ri][4*c+0]=u1.x; uw[1][ri][4*c+1]=u1.y; uw[1][ri][4*c+2]=u1.z; uw[1][ri][4*c+3]=u1.w;
    }
  }
  float bb0 = 0.f, bb1 = 0.f;
  if (layer) { bb0 = bias[DD + rb]; bb1 = bias[DD + rb + 1]; }
  float rown[2][2] = {{0.f, 0.f}, {0.f, 0.f}};  // owned r values (lane 0)
  sh_h[tid] = 0.f;
  sh_h[tid + 512] = 0.f;

  for (int t = 0; t < TT; ++t) {
    const int cu = t & 7, pv = (t - 1) & 7;
    const unsigned ep = (unsigned)((t >> 3) + 1);

    // ---- phase A gates (waves 0 and 1 poll concurrently) ----
    if (wv == 0) {
      if (t > 0) pollgate(tagp(tg, 1, layer, pv, 0), abortf, ln, (unsigned)(((t - 1) >> 3) + 1));
    } else if (wv == 1) {
      if (layer) pollgate(tagp(tg, 0, 0, cu, 0), abortf, ln, ep);               // h1(t) ready
      else if (t >= 8) pollgate(tagp(tg, 1, 1, cu, 0), abortf, ln, (unsigned)(t >> 3));  // bp
    }
    __syncthreads();

    // ---- bulk stage (exactly once per value) ----
    if (layer && tid < 256) {
      f32x4 rv, xv;
      ld4_x2(rS + pv * 2 * DD + 4 * tid, h1s + cu * DD + 4 * tid, rv, xv);
      *(f32x4*)&sh_r[4 * tid] = rv;
      *(f32x4*)&sh_x[4 * tid] = xv;
    } else {
      *(f32x4*)&sh_r[4 * tid] = ld4_x(rS + pv * 2 * DD + 4 * tid);
    }
    float pw0 = 0.f, pw1 = 0.f;
    if (!layer && ln == 0) {
      const f32x2 p2 = *(const f32x2*)&pwx[(size_t)t * DD + rb];
      pw0 = p2.x; pw1 = p2.y;
    }
    __syncthreads();

    // ---- compute 2 pre-rows, publish h_t ----
    float acc0 = 0.f, acc1 = 0.f;
#pragma unroll
    for (int c = 0; c < 4; ++c) {
      const int j = 4 * ln + 256 * c;
      const f32x4 hv = *(const f32x4*)&sh_h[j];
      const f32x4 r0 = *(const f32x4*)&sh_r[j];
      const f32x4 r1v = *(const f32x4*)&sh_r[DD + j];
      acc0 += wh[0][4*c+0]*hv.x + wh[0][4*c+1]*hv.y + wh[0][4*c+2]*hv.z + wh[0][4*c+3]*hv.w
            + wr[0][0][4*c+0]*r0.x + wr[0][0][4*c+1]*r0.y + wr[0][0][4*c+2]*r0.z + wr[0][0][4*c+3]*r0.w
            + wr[0][1][4*c+0]*r1v.x + wr[0][1][4*c+1]*r1v.y + wr[0][1][4*c+2]*r1v.z + wr[0][1][4*c+3]*r1v.w;
      acc1 += wh[1][4*c+0]*hv.x + wh[1][4*c+1]*hv.y + wh[1][4*c+2]*hv.z + wh[1][4*c+3]*hv.w
            + wr[1][0][4*c+0]*r0.x + wr[1][0][4*c+1]*r0.y + wr[1][0][4*c+2]*r0.z + wr[1][0][4*c+3]*r0.w
            + wr[1][1][4*c+0]*r1v.x + wr[1][1][4*c+1]*r1v.y + wr[1][1][4*c+2]*r1v.z + wr[1][1][4*c+3]*r1v.w;
      if (layer) {
        const f32x4 xv = *(const f32x4*)&sh_x[j];
        acc0 += wx[0][4*c+0]*xv.x + wx[0][4*c+1]*xv.y + wx[0][4*c+2]*xv.z + wx[0][4*c+3]*xv.w;
        acc1 += wx[1][4*c+0]*xv.x + wx[1][4*c+1]*xv.y + wx[1][4*c+2]*xv.z + wx[1][4*c+3]*xv.w;
      }
    }
#pragma unroll
    for (int off = 32; off; off >>= 1) {
      acc0 += __shfl_xor(acc0, off, 64);
      acc1 += __shfl_xor(acc1, off, 64);
    }
    if (ln == 0) {
      f32x2 h2;
      h2.x = tanhf(acc0 + (layer ? bb0 : pw0));
      h2.y = tanhf(acc1 + (layer ? bb1 : pw1));
      st2_x(hS + cu * DD + rb, h2);
      if (layer) *(f32x2*)&out[(size_t)t * DD + rb] = h2;
    }
    vdrain();          // this wave's h rows are at the LLC
    __syncthreads();   // all 16 rows of this WG are at the LLC
    if (tid == 0) stu_x(tagp(tg, 0, layer, cu, g), ep);

    // ---- phase B gate: h_t fully ready? ----
    if (wv == 0) pollgate(tagp(tg, 0, layer, cu, 0), abortf, ln, ep);
    __syncthreads();
    if (tid < 256)
      *(f32x4*)&sh_h[4 * tid] = ld4_x(hS + cu * DD + 4 * tid);
    __syncthreads();

    // ---- r update from full h_t (4 owned U-rows), publish r_t ----
    float ua[2][2];
#pragma unroll
    for (int k = 0; k < 2; ++k)
#pragma unroll
      for (int ri = 0; ri < 2; ++ri) {
        float a = 0.f;
#pragma unroll
        for (int c = 0; c < 4; ++c) {
          const int j = 4 * ln + 256 * c;
          const f32x4 hv = *(const f32x4*)&sh_h[j];
          a += uw[k][ri][4*c+0]*hv.x + uw[k][ri][4*c+1]*hv.y
             + uw[k][ri][4*c+2]*hv.z + uw[k][ri][4*c+3]*hv.w;
        }
#pragma unroll
        for (int off = 32; off; off >>= 1) a += __shfl_xor(a, off, 64);
        ua[k][ri] = a;
      }
    if (ln == 0) {
#pragma unroll
      for (int k = 0; k < 2; ++k) {
        rown[k][0] = 0.9f * rown[k][0] + 0.1f * tanhf(ua[k][0]);
        rown[k][1] = 0.9f * rown[k][1] + 0.1f * tanhf(ua[k][1]);
        f32x2 rv; rv.x = rown[k][0]; rv.y = rown[k][1];
        st2_x(rS + cu * 2 * DD + k * DD + rb, rv);
      }
    }
    vdrain();
    __syncthreads();
    if (tid == 0) stu_x(tagp(tg, 1, layer, cu, g), ep);
  }
}

// C[M][1024] = A[M][1024] @ W^T + bias   (W row-major [1024][1024])
__global__ __launch_bounds__(256)
void gemm_bias(const float* __restrict__ A, const float* __restrict__ W,
               const float* __restrict__ bias, float* __restrict__ C) {
  __shared__ float As[32][65];
  __shared__ float Ws[32][65];
  const int tid = threadIdx.x;
  const int bm = blockIdx.x * 64;
  const int bn = blockIdx.y * 64;
  const int ty = tid >> 4, tx = tid & 15;
  float acc[4][4] = {};
  for (int k0 = 0; k0 < DD; k0 += 32) {
#pragma unroll
    for (int p = 0; p < 2; ++p) {
      const int idx = tid + p * 256;
      const int r = idx >> 3;
      const int cf = idx & 7;
      float4 av = *(const float4*)&A[(size_t)(bm + r) * DD + k0 + cf * 4];
      As[cf*4+0][r] = av.x; As[cf*4+1][r] = av.y; As[cf*4+2][r] = av.z; As[cf*4+3][r] = av.w;
      float4 wv = *(const float4*)&W[(size_t)(bn + r) * DD + k0 + cf * 4];
      Ws[cf*4+0][r] = wv.x; Ws[cf*4+1][r] = wv.y; Ws[cf*4+2][r] = wv.z; Ws[cf*4+3][r] = wv.w;
    }
    __syncthreads();
#pragma unroll
    for (int kk = 0; kk < 32; ++kk) {
      float a[4], w[4];
#pragma unroll
      for (int e = 0; e < 4; ++e) { a[e] = As[kk][ty * 4 + e]; w[e] = Ws[kk][tx * 4 + e]; }
#pragma unroll
      for (int i = 0; i < 4; ++i)
#pragma unroll
        for (int j = 0; j < 4; ++j) acc[i][j] += a[i] * w[j];
    }
    __syncthreads();
  }
#pragma unroll
  for (int i = 0; i < 4; ++i) {
    const int m = bm + ty * 4 + i;
#pragma unroll
    for (int j = 0; j < 4; ++j) {
      const int n = bn + tx * 4 + j;
      C[(size_t)m * DD + n] = acc[i][j] + bias[n];
    }
  }
}

extern "C" void kernel_launch(void* const* d_in, const int* in_sizes, int n_in,
                              void* d_out, int out_size, void* d_ws, size_t ws_size,
                              hipStream_t stream) {
  const float* x  = (const float*)d_in[0];
  const float* Wx = (const float*)d_in[1];
  const float* Wh = (const float*)d_in[2];
  const float* Wr = (const float*)d_in[3];
  const float* U  = (const float*)d_in[4];
  const float* b  = (const float*)d_in[5];
  float* out = (float*)d_out;

  float* pwx = (float*)d_ws;                    // [T][D] fp32 = 32 MB
  float* arena = pwx + (size_t)TT * DD;         // 48*DD floats
  unsigned* tg = (unsigned*)(arena + 48 * DD);  // 2*2*8*64*16 + 16 u32 (~128 KB)

  hipLaunchKernelGGL(init_arena, dim3(192), dim3(256), 0, stream, arena, tg);
  hipLaunchKernelGGL(gemm_bias, dim3(TT / 64, DD / 64), dim3(256), 0, stream,
                     x, Wx, b, pwx);  // layer-1 pwx = x @ Wx1^T + b1

  const float* pwxc = pwx;
  float* arenap = arena;
  unsigned* tgp = tg;
  void* args[] = { (void*)&pwxc, (void*)&Wx, (void*)&Wh, (void*)&Wr,
                   (void*)&U, (void*)&b, (void*)&out, (void*)&arenap, (void*)&tgp };
  hipLaunchCooperativeKernel((const void*)crsd_seq, dim3(NWG), dim3(TPB),
                             args, 0, stream);
}

// Round 13
// 34699.051 us; speedup vs baseline: 2.1745x; 1.3197x over previous
//
#include <hip/hip_runtime.h>
#include <math.h>

#define TT 8192
#define DD 1024
#define LWG 64    // WGs per layer
#define NWG 128   // total
#define TPB 512   // 8 waves; each wave owns 2 pre-rows + 4 U-rows
#define GCAP (1 << 15)

typedef __attribute__((ext_vector_type(2))) float f32x2;
typedef __attribute__((ext_vector_type(4))) float f32x4;

// ---- LLC-coherent (cross-XCD) accesses: sc0 sc1 ----
__device__ __forceinline__ void vdrain() { asm volatile("s_waitcnt vmcnt(0)" ::: "memory"); }
__device__ __forceinline__ void st4_x(float* p, f32x4 v) {
  asm volatile("global_store_dwordx4 %0, %1, off sc0 sc1" :: "v"(p), "v"(v) : "memory");
}
__device__ __forceinline__ void stu_x(unsigned* p, unsigned v) {
  asm volatile("global_store_dword %0, %1, off sc0 sc1" :: "v"(p), "v"(v) : "memory");
}
__device__ __forceinline__ f32x4 ld4_x(const float* p) {
  f32x4 r;
  asm volatile("global_load_dwordx4 %0, %1, off sc0 sc1\n\ts_waitcnt vmcnt(0)"
               : "=&v"(r) : "v"(p) : "memory");
  return r;
}
__device__ __forceinline__ void ld4_x2(const float* p0, const float* p1, f32x4& a, f32x4& b) {
  asm volatile("global_load_dwordx4 %0, %2, off sc0 sc1\n\t"
               "global_load_dwordx4 %1, %3, off sc0 sc1\n\t"
               "s_waitcnt vmcnt(0)"
               : "=&v"(a), "=&v"(b) : "v"(p0), "v"(p1) : "memory");
}
__device__ __forceinline__ unsigned ldu_x(const unsigned* p) {
  unsigned r;
  asm volatile("global_load_dword %0, %1, off sc0 sc1\n\ts_waitcnt vmcnt(0)"
               : "=&v"(r) : "v"(p) : "memory");
  return r;
}

// Epoch-tuple poll: one aligned 16B load carries {v0, v1, epoch, pad} — a single
// dwordx4 store is one LLC transaction, so flag and data arrive atomically.
__device__ __forceinline__ f32x4 pollep(const float* p, float epf, unsigned* abortf) {
  int g = 0;
  for (;;) {
    f32x4 v = ld4_x(p);
    if (v.z == epf) return v;
    if ((++g & 255) == 0) {
      if (ldu_x(abortf)) return v;
      if (g > GCAP) { stu_x(abortf, 1u); vdrain(); return v; }
    }
    if (g & 2) __builtin_amdgcn_s_sleep(1);
  }
}
__device__ __forceinline__ void pollep2(const float* p0, const float* p1, float epf,
                                        unsigned* abortf, f32x4& a, f32x4& b) {
  int g = 0;
  for (;;) {
    ld4_x2(p0, p1, a, b);
    if (a.z == epf && b.z == epf) return;
    if ((++g & 255) == 0) {
      if (ldu_x(abortf)) return;
      if (g > GCAP) { stu_x(abortf, 1u); vdrain(); return; }
    }
    if (g & 2) __builtin_amdgcn_s_sleep(1);
  }
}

// arena: hT[2][8][512] f32x4 tuples | rT[2][2][2][512] f32x4 tuples (all epochs 0)
#define HT_FLOATS (2 * 8 * 512 * 4)
#define RT_FLOATS (2 * 2 * 2 * 512 * 4)
__global__ void init_arena(float* __restrict__ arena, unsigned* __restrict__ tg) {
  const int idx = blockIdx.x * 256 + threadIdx.x;
  if (idx < HT_FLOATS + RT_FLOATS) arena[idx] = 0.f;
  if (idx < 2048) tg[idx] = 0u;
}

// Persistent 2-layer CRSD, fused epoch-tuple exchange (1 LLC RT per leg).
// WGs 0..63: layer 1; 64..127: layer 2 (consumes h1(t) same tick).
// Wave wv of g owns pre-rows rb=g*16+2*wv..+1 and U-rows (k,rb),(k,rb+1).
// Tuple idx for (g,wv) = g*8+wv; consumer thread tid owns rows 2*tid,2*tid+1.
// Slots: h 8-deep (epoch-checked; h1 overwrite gated on L2 stamps >= t-7),
//        r 2-deep (phase-A r-poll proves all own-layer WGs finished tick t-1).
__global__ __launch_bounds__(TPB, 1)
void crsd_seq(const float* __restrict__ pwx, const float* __restrict__ Wx,
              const float* __restrict__ Wh, const float* __restrict__ Wr,
              const float* __restrict__ Uw, const float* __restrict__ bias,
              float* __restrict__ out, float* __restrict__ arena,
              unsigned* __restrict__ tg) {
  const int wg = blockIdx.x, tid = threadIdx.x;
  const int wv = tid >> 6, ln = tid & 63;
  const int layer = wg >> 6, g = wg & 63;
  const int rb = g * 16 + 2 * wv;
  const size_t MS = (size_t)DD * DD;

  float* hT0 = arena;                         // layer-1 h tuples
  float* hTL = arena + (size_t)layer * 8 * 512 * 4;
  float* rT  = arena + HT_FLOATS;
  unsigned* stamp = tg;                        // 64 L2-WG stamps, 64B-padded
  unsigned* abortf = tg + 1024;

  __shared__ __align__(16) float sh_x[DD];
  __shared__ __align__(16) float sh_h[DD];
  __shared__ __align__(16) float sh_r[2 * DD];

  const float* Whp = Wh + (size_t)layer * MS;
  const float* Wrp = Wr + (size_t)layer * 2 * MS;
  const float* Up  = Uw + (size_t)layer * 2 * MS;

  // ---- one-time weight load into registers (2 pre-rows + 4 U-rows per wave) ----
  float wh[2][16], wr[2][2][16], wx[2][16], uw[2][2][16];
#pragma unroll
  for (int ri = 0; ri < 2; ++ri) {
    const int row = rb + ri;
#pragma unroll
    for (int c = 0; c < 4; ++c) {
      const int j = 4 * ln + 256 * c;
      f32x4 a = *(const f32x4*)&Whp[(size_t)row * DD + j];
      wh[ri][4*c+0]=a.x; wh[ri][4*c+1]=a.y; wh[ri][4*c+2]=a.z; wh[ri][4*c+3]=a.w;
      f32x4 b0 = *(const f32x4*)&Wrp[(size_t)row * DD + j];
      wr[ri][0][4*c+0]=b0.x; wr[ri][0][4*c+1]=b0.y; wr[ri][0][4*c+2]=b0.z; wr[ri][0][4*c+3]=b0.w;
      f32x4 b1 = *(const f32x4*)&Wrp[MS + (size_t)row * DD + j];
      wr[ri][1][4*c+0]=b1.x; wr[ri][1][4*c+1]=b1.y; wr[ri][1][4*c+2]=b1.z; wr[ri][1][4*c+3]=b1.w;
      if (layer) {
        f32x4 xw = *(const f32x4*)&Wx[MS + (size_t)row * DD + j];
        wx[ri][4*c+0]=xw.x; wx[ri][4*c+1]=xw.y; wx[ri][4*c+2]=xw.z; wx[ri][4*c+3]=xw.w;
      } else {
        wx[ri][4*c+0]=0.f; wx[ri][4*c+1]=0.f; wx[ri][4*c+2]=0.f; wx[ri][4*c+3]=0.f;
      }
      f32x4 u0 = *(const f32x4*)&Up[(size_t)row * DD + j];
      uw[0][ri][4*c+0]=u0.x; uw[0][ri][4*c+1]=u0.y; uw[0][ri][4*c+2]=u0.z; uw[0][ri][4*c+3]=u0.w;
      f32x4 u1 = *(const f32x4*)&Up[MS + (size_t)row * DD + j];
      uw[1][ri][4*c+0]=u1.x; uw[1][ri][4*c+1]=u1.y; uw[1][ri][4*c+2]=u1.z; uw[1][ri][4*c+3]=u1.w;
    }
  }
  float bb0 = 0.f, bb1 = 0.f;
  if (layer) { bb0 = bias[DD + rb]; bb1 = bias[DD + rb + 1]; }
  float rown[2][2] = {{0.f, 0.f}, {0.f, 0.f}};
  sh_h[tid] = 0.f;
  sh_h[tid + 512] = 0.f;

  for (int t = 0; t < TT; ++t) {
    const int cu = t & 7;
    const float eph = (float)(t + 1);      // epoch of tick-t publishes

    // ---- phase A: stage r(t-1) (+x=h1(t) for L2); L1 wave0 runs stamp gate ----
    if (t > 0) {
      const float epr = (float)t;          // r(t-1) epoch
      const int ps = (t - 1) & 1;
      f32x4 ra, rc;
      pollep2(rT + ((((size_t)(layer * 2 + 0) * 2 + ps) * 512) + tid) * 4,
              rT + ((((size_t)(layer * 2 + 1) * 2 + ps) * 512) + tid) * 4,
              epr, abortf, ra, rc);
      f32x2 w0; w0.x = ra.x; w0.y = ra.y;
      f32x2 w1; w1.x = rc.x; w1.y = rc.y;
      *(f32x2*)&sh_r[2 * tid] = w0;
      *(f32x2*)&sh_r[1024 + 2 * tid] = w1;
    } else {
      sh_r[2 * tid] = 0.f; sh_r[2 * tid + 1] = 0.f;
      sh_r[1024 + 2 * tid] = 0.f; sh_r[1024 + 2 * tid + 1] = 0.f;
    }
    if (layer) {
      f32x4 xv = pollep(hT0 + ((size_t)cu * 512 + tid) * 4, eph, abortf);
      f32x2 wxv; wxv.x = xv.x; wxv.y = xv.y;
      *(f32x2*)&sh_x[2 * tid] = wxv;
    } else if (wv == 0 && t >= 8) {
      // h1-slot reuse gate: all 64 L2 WGs consumed h1(t-8)  (stamp >= t-7)
      const unsigned tgt = (unsigned)(t - 7);
      const unsigned* sp = stamp + (ln << 4);
      int gg = 0;
      for (;;) {
        const unsigned v = ldu_x(sp);
        if (__all((int)(v >= tgt))) break;
        if ((++gg & 255) == 0) {
          if (ldu_x(abortf)) break;
          if (gg > GCAP) { stu_x(abortf, 1u); vdrain(); break; }
        }
        __builtin_amdgcn_s_sleep(1);
      }
    }
    float pw0 = 0.f, pw1 = 0.f;
    if (!layer && ln == 0) {
      const f32x2 p2 = *(const f32x2*)&pwx[(size_t)t * DD + rb];
      pw0 = p2.x; pw1 = p2.y;
    }
    __syncthreads();
    if (layer && tid == 0) stu_x(stamp + (g << 4), (unsigned)(t + 1));  // consumed h1(t)

    // ---- compute 2 pre-rows, publish h(t) tuple ----
    float acc0 = 0.f, acc1 = 0.f;
#pragma unroll
    for (int c = 0; c < 4; ++c) {
      const int j = 4 * ln + 256 * c;
      const f32x4 hv = *(const f32x4*)&sh_h[j];
      const f32x4 r0 = *(const f32x4*)&sh_r[j];
      const f32x4 r1v = *(const f32x4*)&sh_r[DD + j];
      acc0 += wh[0][4*c+0]*hv.x + wh[0][4*c+1]*hv.y + wh[0][4*c+2]*hv.z + wh[0][4*c+3]*hv.w
            + wr[0][0][4*c+0]*r0.x + wr[0][0][4*c+1]*r0.y + wr[0][0][4*c+2]*r0.z + wr[0][0][4*c+3]*r0.w
            + wr[0][1][4*c+0]*r1v.x + wr[0][1][4*c+1]*r1v.y + wr[0][1][4*c+2]*r1v.z + wr[0][1][4*c+3]*r1v.w;
      acc1 += wh[1][4*c+0]*hv.x + wh[1][4*c+1]*hv.y + wh[1][4*c+2]*hv.z + wh[1][4*c+3]*hv.w
            + wr[1][0][4*c+0]*r0.x + wr[1][0][4*c+1]*r0.y + wr[1][0][4*c+2]*r0.z + wr[1][0][4*c+3]*r0.w
            + wr[1][1][4*c+0]*r1v.x + wr[1][1][4*c+1]*r1v.y + wr[1][1][4*c+2]*r1v.z + wr[1][1][4*c+3]*r1v.w;
      if (layer) {
        const f32x4 xv = *(const f32x4*)&sh_x[j];
        acc0 += wx[0][4*c+0]*xv.x + wx[0][4*c+1]*xv.y + wx[0][4*c+2]*xv.z + wx[0][4*c+3]*xv.w;
        acc1 += wx[1][4*c+0]*xv.x + wx[1][4*c+1]*xv.y + wx[1][4*c+2]*xv.z + wx[1][4*c+3]*xv.w;
      }
    }
#pragma unroll
    for (int off = 32; off; off >>= 1) {
      acc0 += __shfl_xor(acc0, off, 64);
      acc1 += __shfl_xor(acc1, off, 64);
    }
    if (ln == 0) {
      f32x4 ht;
      ht.x = tanhf(acc0 + (layer ? bb0 : pw0));
      ht.y = tanhf(acc1 + (layer ? bb1 : pw1));
      ht.z = eph; ht.w = 0.f;
      st4_x(hTL + ((size_t)cu * 512 + g * 8 + wv) * 4, ht);   // flag+data, 1 store
      if (layer) {
        f32x2 ov; ov.x = ht.x; ov.y = ht.y;
        *(f32x2*)&out[(size_t)t * DD + rb] = ov;
      }
    }
    if (t == TT - 1) break;          // last tick: nothing consumes r(TT-1)/h-phase-B
    __syncthreads();                 // protect sh_h readers before re-fill

    // ---- phase B: gather full h(t), update owned r rows, publish r tuples ----
    {
      f32x4 hv4 = pollep(hTL + ((size_t)cu * 512 + tid) * 4, eph, abortf);
      f32x2 wh2; wh2.x = hv4.x; wh2.y = hv4.y;
      *(f32x2*)&sh_h[2 * tid] = wh2;
    }
    __syncthreads();

    float ua[2][2];
#pragma unroll
    for (int k = 0; k < 2; ++k)
#pragma unroll
      for (int ri = 0; ri < 2; ++ri) {
        float a = 0.f;
#pragma unroll
        for (int c = 0; c < 4; ++c) {
          const int j = 4 * ln + 256 * c;
          const f32x4 hv = *(const f32x4*)&sh_h[j];
          a += uw[k][ri][4*c+0]*hv.x + uw[k][ri][4*c+1]*hv.y
             + uw[k][ri][4*c+2]*hv.z + uw[k][ri][4*c+3]*hv.w;
        }
#pragma unroll
        for (int off = 32; off; off >>= 1) a += __shfl_xor(a, off, 64);
        ua[k][ri] = a;
      }
    if (ln == 0) {
      const int ps = t & 1;
#pragma unroll
      for (int k = 0; k < 2; ++k) {
        rown[k][0] = 0.9f * rown[k][0] + 0.1f * tanhf(ua[k][0]);
        rown[k][1] = 0.9f * rown[k][1] + 0.1f * tanhf(ua[k][1]);
        f32x4 rt;
        rt.x = rown[k][0]; rt.y = rown[k][1]; rt.z = eph; rt.w = 0.f;
        st4_x(rT + ((((size_t)(layer * 2 + k) * 2 + ps) * 512) + g * 8 + wv) * 4, rt);
      }
    }
  }
}

// C[M][1024] = A[M][1024] @ W^T + bias   (W row-major [1024][1024])
__global__ __launch_bounds__(256)
void gemm_bias(const float* __restrict__ A, const float* __restrict__ W,
               const float* __restrict__ bias, float* __restrict__ C) {
  __shared__ float As[32][65];
  __shared__ float Ws[32][65];
  const int tid = threadIdx.x;
  const int bm = blockIdx.x * 64;
  const int bn = blockIdx.y * 64;
  const int ty = tid >> 4, tx = tid & 15;
  float acc[4][4] = {};
  for (int k0 = 0; k0 < DD; k0 += 32) {
#pragma unroll
    for (int p = 0; p < 2; ++p) {
      const int idx = tid + p * 256;
      const int r = idx >> 3;
      const int cf = idx & 7;
      float4 av = *(const float4*)&A[(size_t)(bm + r) * DD + k0 + cf * 4];
      As[cf*4+0][r] = av.x; As[cf*4+1][r] = av.y; As[cf*4+2][r] = av.z; As[cf*4+3][r] = av.w;
      float4 wv = *(const float4*)&W[(size_t)(bn + r) * DD + k0 + cf * 4];
      Ws[cf*4+0][r] = wv.x; Ws[cf*4+1][r] = wv.y; Ws[cf*4+2][r] = wv.z; Ws[cf*4+3][r] = wv.w;
    }
    __syncthreads();
#pragma unroll
    for (int kk = 0; kk < 32; ++kk) {
      float a[4], w[4];
#pragma unroll
      for (int e = 0; e < 4; ++e) { a[e] = As[kk][ty * 4 + e]; w[e] = Ws[kk][tx * 4 + e]; }
#pragma unroll
      for (int i = 0; i < 4; ++i)
#pragma unroll
        for (int j = 0; j < 4; ++j) acc[i][j] += a[i] * w[j];
    }
    __syncthreads();
  }
#pragma unroll
  for (int i = 0; i < 4; ++i) {
    const int m = bm + ty * 4 + i;
#pragma unroll
    for (int j = 0; j < 4; ++j) {
      const int n = bn + tx * 4 + j;
      C[(size_t)m * DD + n] = acc[i][j] + bias[n];
    }
  }
}

extern "C" void kernel_launch(void* const* d_in, const int* in_sizes, int n_in,
                              void* d_out, int out_size, void* d_ws, size_t ws_size,
                              hipStream_t stream) {
  const float* x  = (const float*)d_in[0];
  const float* Wx = (const float*)d_in[1];
  const float* Wh = (const float*)d_in[2];
  const float* Wr = (const float*)d_in[3];
  const float* U  = (const float*)d_in[4];
  const float* b  = (const float*)d_in[5];
  float* out = (float*)d_out;

  float* pwx = (float*)d_ws;                             // [T][D] fp32 = 32 MB
  float* arena = pwx + (size_t)TT * DD;                  // hT + rT tuples
  unsigned* tg = (unsigned*)(arena + HT_FLOATS + RT_FLOATS);  // stamps + abort

  hipLaunchKernelGGL(init_arena, dim3(192), dim3(256), 0, stream, arena, tg);
  hipLaunchKernelGGL(gemm_bias, dim3(TT / 64, DD / 64), dim3(256), 0, stream,
                     x, Wx, b, pwx);  // layer-1 pwx = x @ Wx1^T + b1

  const float* pwxc = pwx;
  float* arenap = arena;
  unsigned* tgp = tg;
  void* args[] = { (void*)&pwxc, (void*)&Wx, (void*)&Wh, (void*)&Wr,
                   (void*)&U, (void*)&b, (void*)&out, (void*)&arenap, (void*)&tgp };
  hipLaunchCooperativeKernel((const void*)crsd_seq, dim3(NWG), dim3(TPB),
                             args, 0, stream);
}